// Round 2
// baseline (6566.685 us; speedup 1.0000x reference)
//
#include <hip/hip_runtime.h>

#define B_ 64
#define T_ 256
#define H_ 1024
#define D_ 409
#define NWG 256
#define RING 64

typedef _Float16 h8 __attribute__((ext_vector_type(8)));
typedef float f4 __attribute__((ext_vector_type(4)));

__device__ __forceinline__ float sigf(float x) {
  return 1.f / (1.f + __expf(-x));
}
__device__ __forceinline__ float tanhf_(float x) {
  return 1.f - 2.f / (1.f + __expf(2.f * x));   // saturates correctly
}

// ---------------- prep: pack x and pred_W into fp16 MFMA fragment layouts ---
// A-frag (16x16x32): lane l holds row (l&15), k = 8*(l>>4)+e
// B-frag:            lane l holds col (l&15), k = 8*(l>>4)+e
__global__ __launch_bounds__(256) void prep_kernel(
    const float* __restrict__ inp, const float* __restrict__ Pw,
    _Float16* __restrict__ xP, _Float16* __restrict__ PP,
    int* __restrict__ flags)
{
  const int NX = 256 * 4 * 13 * 64;   // x frags: [t][mt][kc][lane] x 8
  const int NP = 26 * 32 * 64;        // pred frags: [nt][kc][lane] x 8
  int gid = blockIdx.x * 256 + threadIdx.x;
  if (gid < NWG) flags[gid] = 0;
  if (gid < NX) {
    int lane = gid & 63; int q = gid >> 6;
    int kc = q % 13; q /= 13;
    int mt = q & 3;  int t = q >> 2;
    const float* src = inp + ((size_t)(16 * mt + (lane & 15)) * T_ + t) * D_;
    int k0 = kc * 32 + 8 * (lane >> 4);
    h8 v;
#pragma unroll
    for (int e = 0; e < 8; ++e) {
      int k = k0 + e;
      v[e] = (k < D_) ? (_Float16)src[k] : (_Float16)0.f;
    }
    *(h8*)(xP + (size_t)gid * 8) = v;
  } else if (gid < NX + NP) {
    int r = gid - NX;
    int lane = r & 63; int q = r >> 6;
    int kc = q & 31; int nt = q >> 5;
    int n = nt * 16 + (lane & 15);
    int k0 = kc * 32 + 8 * (lane >> 4);
    h8 v;
#pragma unroll
    for (int e = 0; e < 8; ++e)
      v[e] = (n < D_) ? (_Float16)Pw[(size_t)n * H_ + k0 + e] : (_Float16)0.f;
    *(h8*)(PP + (size_t)r * 8) = v;
  }
}

// ---------------- persistent recurrent kernel: 256 WGs x 256 threads --------
// WG w owns hidden units [4w, 4w+4) -> 16 gate-cols, col c = 4*uu + g.
// Wave m = split-K slice [256m, 256m+256) of Whh (hi+lo fp16 resident VGPRs).
// h published fp16 into 64-slot ring; flags monotonic step tags (agent scope).
__global__ __launch_bounds__(256, 1) void recur_kernel(
    const float* __restrict__ eWhh, const float* __restrict__ eb,
    const float* __restrict__ dWhh, const float* __restrict__ db,
    const float* __restrict__ eWih, const float* __restrict__ dWih,
    const _Float16* __restrict__ xP, _Float16* __restrict__ ring,
    _Float16* __restrict__ hs, int* __restrict__ flags,
    float* __restrict__ latents)
{
  __shared__ float red[4 * 64 * 20];   // [wave][row(b)][col] stride 20

  const int tid  = threadIdx.x;
  const int w    = blockIdx.x;
  const int m    = tid >> 6;
  const int lane = tid & 63;
  const int ci   = lane & 15;      // this lane's output col 0..15
  const int q    = lane >> 4;
  const int uu   = ci >> 2, g = ci & 3;
  const int nrow = g * H_ + 4 * w + uu;   // W row for this col
  const int eb_  = tid >> 2, euu = tid & 3;  // epilogue (b, unit)

  h8 Whi[8], Wlo[8], Ihi[4], Ilo[4];
  float bias4[4];
  float c_reg = 0.f;
  const int kbeg = (m == 0) ? 0 : (3 * m + 1);
  const int kend = 3 * m + 4;
  const int nkc  = kend - kbeg;

#pragma unroll 1
  for (int s = 1; s <= 512; ++s) {
    if (s == 1 || s == 257) {
      const float* Whh = (s == 1) ? eWhh : dWhh;
      const float* Wih = (s == 1) ? eWih : dWih;
      const float* bb  = (s == 1) ? eb : db;
#pragma unroll
      for (int kc = 0; kc < 8; ++kc) {
        const float* p = Whh + (size_t)nrow * H_ + m * 256 + kc * 32 + 8 * q;
#pragma unroll
        for (int e = 0; e < 8; ++e) {
          float wf = p[e];
          _Float16 hi = (_Float16)wf;
          Whi[kc][e] = hi;
          Wlo[kc][e] = (_Float16)(wf - (float)hi);
        }
      }
      for (int j = 0; j < 4; ++j) {
        if (j < nkc) {
          int kc = kbeg + j;
          int k0 = kc * 32 + 8 * q;
#pragma unroll
          for (int e = 0; e < 8; ++e) {
            int k = k0 + e;
            float wf = (k < D_) ? Wih[(size_t)nrow * D_ + k] : 0.f;
            _Float16 hi = (_Float16)wf;
            Ihi[j][e] = hi;
            Ilo[j][e] = (_Float16)(wf - (float)hi);
          }
        }
      }
#pragma unroll
      for (int g2 = 0; g2 < 4; ++g2)
        bias4[g2] = bb[g2 * H_ + 4 * w + euu];
    }

    const bool have_h = (s > 1);
    const int  t_x    = (s <= 256) ? (s - 1) : (s - 258);
    const bool have_x = (t_x >= 0);

    if (have_h) {
      int* fp = flags + tid;
      const int target = s - 1;
      int it = 0;
      while (__hip_atomic_load(fp, __ATOMIC_RELAXED, __HIP_MEMORY_SCOPE_AGENT) < target) {
        if (++it > (1 << 20)) break;   // safety valve (diagnosable, not silent)
        __builtin_amdgcn_s_sleep(1);
      }
      __syncthreads();
      if (s == 2 || (s & 63) == 0)
        __builtin_amdgcn_fence(__ATOMIC_ACQUIRE, "agent");  // L1/L2 inv: ring reuse + cross-launch staleness
      asm volatile("" ::: "memory");   // compiler: no sinking of h-loads above poll
    }

    f4 acc[4];
#pragma unroll
    for (int mt = 0; mt < 4; ++mt) { f4 z = {0.f, 0.f, 0.f, 0.f}; acc[mt] = z; }

    if (have_x) {
      for (int j = 0; j < 4; ++j) {
        if (j < nkc) {
          int kc = kbeg + j;
#pragma unroll
          for (int mt = 0; mt < 4; ++mt) {
            h8 a = *(const h8*)(xP + ((size_t)((t_x * 4 + mt) * 13 + kc) * 64 + lane) * 8);
            acc[mt] = __builtin_amdgcn_mfma_f32_16x16x32_f16(a, Ihi[j], acc[mt], 0, 0, 0);
            acc[mt] = __builtin_amdgcn_mfma_f32_16x16x32_f16(a, Ilo[j], acc[mt], 0, 0, 0);
          }
        }
      }
    }

    if (have_h) {
      const _Float16* hb = ring + (size_t)((s - 1) & (RING - 1)) * (B_ * H_);
#pragma unroll
      for (int kc = 0; kc < 8; ++kc) {
#pragma unroll
        for (int mt = 0; mt < 4; ++mt) {
          h8 a = *(const h8*)(hb + (size_t)(16 * mt + ci) * H_ + m * 256 + kc * 32 + 8 * q);
          acc[mt] = __builtin_amdgcn_mfma_f32_16x16x32_f16(a, Whi[kc], acc[mt], 0, 0, 0);
          acc[mt] = __builtin_amdgcn_mfma_f32_16x16x32_f16(a, Wlo[kc], acc[mt], 0, 0, 0);
        }
      }
    }

    // split-K partials -> LDS
#pragma unroll
    for (int mt = 0; mt < 4; ++mt)
#pragma unroll
      for (int r = 0; r < 4; ++r)
        red[(m * 64 + 16 * mt + 4 * q + r) * 20 + ci] = acc[mt][r];
    __syncthreads();

    // epilogue: thread owns (b=eb_, unit uu=euu); cols 4*euu..+3 = gates i,f,g,o
    f4 sum = *(const f4*)(&red[(0 * 64 + eb_) * 20 + 4 * euu]);
#pragma unroll
    for (int mv = 1; mv < 4; ++mv)
      sum += *(const f4*)(&red[(mv * 64 + eb_) * 20 + 4 * euu]);
    float gi = sum[0] + bias4[0];
    float gf = sum[1] + bias4[1];
    float gg = sum[2] + bias4[2];
    float go = sum[3] + bias4[3];
    float cold = have_h ? c_reg : 0.f;
    float cn = sigf(gf) * cold + sigf(gi) * tanhf_(gg);
    float hn = sigf(go) * tanhf_(cn);
    c_reg = cn;
    _Float16 h16 = (_Float16)hn;
    ring[(size_t)(s & (RING - 1)) * (B_ * H_) + (size_t)eb_ * H_ + 4 * w + euu] = h16;
    if (s > 256)
      hs[(size_t)(s - 257) * (B_ * H_) + (size_t)eb_ * H_ + 4 * w + euu] = h16;
    if (s == 256)
      latents[(size_t)eb_ * H_ + 4 * w + euu] = hn;

    asm volatile("s_waitcnt vmcnt(0)" ::: "memory");  // every wave drains stores
    __syncthreads();
    if (tid == 0)
      __hip_atomic_store(flags + w, s, __ATOMIC_RELEASE, __HIP_MEMORY_SCOPE_AGENT);
  }
}

// ---------------- prediction head: [16384,1024] @ [1024,409] + bias ---------
__global__ __launch_bounds__(256) void pred_kernel(
    const _Float16* __restrict__ hs, const _Float16* __restrict__ PP,
    const float* __restrict__ pb, float* __restrict__ outseq)
{
  int wt = blockIdx.x * 4 + (threadIdx.x >> 6);
  int lane = threadIdx.x & 63;
  int nt = wt % 26, mt = wt / 26;
  int i = lane & 15, q = lane >> 4;
  int n = nt * 16 + i;
  float bias = (n < D_) ? pb[n] : 0.f;
  f4 acc = {bias, bias, bias, bias};
  int R = mt * 16;
#pragma unroll 4
  for (int kc = 0; kc < 32; ++kc) {
    h8 a = *(const h8*)(hs + (size_t)(R + i) * H_ + kc * 32 + 8 * q);
    h8 b = *(const h8*)(PP + ((size_t)(nt * 32 + kc) * 64 + lane) * 8);
    acc = __builtin_amdgcn_mfma_f32_16x16x32_f16(a, b, acc, 0, 0, 0);
  }
#pragma unroll
  for (int r = 0; r < 4; ++r) {
    int row = R + 4 * q + r;       // row = t*64 + b
    int t = row >> 6, bb = row & 63;
    if (n < D_) outseq[((size_t)bb * T_ + t) * D_ + n] = acc[r];
  }
}

extern "C" void kernel_launch(void* const* d_in, const int* in_sizes, int n_in,
                              void* d_out, int out_size, void* d_ws, size_t ws_size,
                              hipStream_t stream) {
  const float* inp  = (const float*)d_in[0];
  const float* eWih = (const float*)d_in[1];
  const float* eWhh = (const float*)d_in[2];
  const float* eb   = (const float*)d_in[3];
  const float* dWih = (const float*)d_in[4];
  const float* dWhh = (const float*)d_in[5];
  const float* db   = (const float*)d_in[6];
  const float* pW   = (const float*)d_in[7];
  const float* pb   = (const float*)d_in[8];
  float* out = (float*)d_out;
  float* latents = out;              // [1,64,1024]
  float* seq = out + 64 * 1024;      // [64,256,409]

  char* ws = (char*)d_ws;
  size_t off = 0;
  auto alloc = [&](size_t bytes) {
    void* p = ws + off;
    off = (off + bytes + 255) & ~(size_t)255;
    return p;
  };
  _Float16* xP  = (_Float16*)alloc((size_t)256 * 4 * 13 * 64 * 8 * 2);
  _Float16* PP  = (_Float16*)alloc((size_t)26 * 32 * 64 * 8 * 2);
  _Float16* ring= (_Float16*)alloc((size_t)RING * B_ * H_ * 2);
  _Float16* hsb = (_Float16*)alloc((size_t)256 * B_ * H_ * 2);
  int* flags    = (int*)alloc(NWG * 4);

  hipLaunchKernelGGL(prep_kernel, dim3(3536), dim3(256), 0, stream,
                     inp, pW, xP, PP, flags);
  hipLaunchKernelGGL(recur_kernel, dim3(NWG), dim3(256), 0, stream,
                     eWhh, eb, dWhh, db, eWih, dWih, xP, ring, hsb, flags, latents);
  hipLaunchKernelGGL(pred_kernel, dim3(6656), dim3(256), 0, stream,
                     hsb, PP, pb, seq);
}

// Round 3
// 5737.608 us; speedup vs baseline: 1.1445x; 1.1445x over previous
//
#include <hip/hip_runtime.h>

#define B_ 64
#define T_ 256
#define H_ 1024
#define D_ 409
#define NWG 256
#define RING 8

typedef _Float16 h8 __attribute__((ext_vector_type(8)));
typedef float f4 __attribute__((ext_vector_type(4)));
typedef unsigned long long u64t;

__device__ __forceinline__ float sigf(float x) {
  return 1.f / (1.f + __expf(-x));
}
__device__ __forceinline__ float tanhf_(float x) {
  return 1.f - 2.f / (1.f + __expf(2.f * x));   // saturates correctly
}

// device-coherent (sc1) 16-byte h load as two relaxed agent-scope 8B atomics
__device__ __forceinline__ h8 load_h16_agent(const _Float16* p) {
  const u64t* q = (const u64t*)p;
  union { h8 v; u64t q[2]; } u;
  u.q[0] = __hip_atomic_load(q,     __ATOMIC_RELAXED, __HIP_MEMORY_SCOPE_AGENT);
  u.q[1] = __hip_atomic_load(q + 1, __ATOMIC_RELAXED, __HIP_MEMORY_SCOPE_AGENT);
  return u.v;
}

// ---------------- prep: pack x and pred_W into fp16 MFMA fragment layouts ---
// A-frag (16x16x32): lane l holds row (l&15), k = 8*(l>>4)+e
// B-frag:            lane l holds col (l&15), k = 8*(l>>4)+e
__global__ __launch_bounds__(256) void prep_kernel(
    const float* __restrict__ inp, const float* __restrict__ Pw,
    _Float16* __restrict__ xP, _Float16* __restrict__ PP,
    int* __restrict__ flags)
{
  const int NX = 256 * 4 * 13 * 64;   // x frags: [t][mt][kc][lane] x 8
  const int NP = 26 * 32 * 64;        // pred frags: [nt][kc][lane] x 8
  int gid = blockIdx.x * 256 + threadIdx.x;
  if (gid < NWG) flags[gid] = 0;
  if (gid < NX) {
    int lane = gid & 63; int q = gid >> 6;
    int kc = q % 13; q /= 13;
    int mt = q & 3;  int t = q >> 2;
    const float* src = inp + ((size_t)(16 * mt + (lane & 15)) * T_ + t) * D_;
    int k0 = kc * 32 + 8 * (lane >> 4);
    h8 v;
#pragma unroll
    for (int e = 0; e < 8; ++e) {
      int k = k0 + e;
      v[e] = (k < D_) ? (_Float16)src[k] : (_Float16)0.f;
    }
    *(h8*)(xP + (size_t)gid * 8) = v;
  } else if (gid < NX + NP) {
    int r = gid - NX;
    int lane = r & 63; int q = r >> 6;
    int kc = q & 31; int nt = q >> 5;
    int n = nt * 16 + (lane & 15);
    int k0 = kc * 32 + 8 * (lane >> 4);
    h8 v;
#pragma unroll
    for (int e = 0; e < 8; ++e)
      v[e] = (n < D_) ? (_Float16)Pw[(size_t)n * H_ + k0 + e] : (_Float16)0.f;
    *(h8*)(PP + (size_t)r * 8) = v;
  }
}

// ---------------- persistent recurrent kernel: 256 WGs x 256 threads --------
// WG w owns hidden units [4w, 4w+4) -> 16 gate-cols, col c = 4*uu + g.
// Wave m = split-K slice [256m, 256m+256) of Whh (hi+lo fp16 resident VGPRs).
// h exchanged via 8-slot ring with sc1 (device-coherent) loads/stores; flags
// are monotonic step tags, relaxed agent atomics; NO cache-flush fences.
__global__ __launch_bounds__(256, 1) void recur_kernel(
    const float* __restrict__ eWhh, const float* __restrict__ eb,
    const float* __restrict__ dWhh, const float* __restrict__ db,
    const float* __restrict__ eWih, const float* __restrict__ dWih,
    const _Float16* __restrict__ xP, _Float16* __restrict__ ring,
    _Float16* __restrict__ hs, int* __restrict__ flags,
    float* __restrict__ latents)
{
  __shared__ float red[4 * 64 * 20];   // [wave][row(b)][col] stride 20

  const int tid  = threadIdx.x;
  const int w    = blockIdx.x;
  const int m    = tid >> 6;
  const int lane = tid & 63;
  const int ci   = lane & 15;      // this lane's output col 0..15
  const int q    = lane >> 4;
  const int uu   = ci >> 2, g = ci & 3;
  const int nrow = g * H_ + 4 * w + uu;   // W row for this col
  const int eb_  = tid >> 2, euu = tid & 3;  // epilogue (b, unit)

  h8 Whi[8], Wlo[8], Ihi[4], Ilo[4];
  float bias4[4];
  float c_reg = 0.f;
  const int kbeg = (m == 0) ? 0 : (3 * m + 1);
  const int kend = 3 * m + 4;
  const int nkc  = kend - kbeg;

#pragma unroll 1
  for (int s = 1; s <= 512; ++s) {
    if (s == 1 || s == 257) {
      const float* Whh = (s == 1) ? eWhh : dWhh;
      const float* Wih = (s == 1) ? eWih : dWih;
      const float* bb  = (s == 1) ? eb : db;
#pragma unroll
      for (int kc = 0; kc < 8; ++kc) {
        const float* p = Whh + (size_t)nrow * H_ + m * 256 + kc * 32 + 8 * q;
#pragma unroll
        for (int e = 0; e < 8; ++e) {
          float wf = p[e];
          _Float16 hi = (_Float16)wf;
          Whi[kc][e] = hi;
          Wlo[kc][e] = (_Float16)(wf - (float)hi);
        }
      }
      for (int j = 0; j < 4; ++j) {
        if (j < nkc) {
          int kc = kbeg + j;
          int k0 = kc * 32 + 8 * q;
#pragma unroll
          for (int e = 0; e < 8; ++e) {
            int k = k0 + e;
            float wf = (k < D_) ? Wih[(size_t)nrow * D_ + k] : 0.f;
            _Float16 hi = (_Float16)wf;
            Ihi[j][e] = hi;
            Ilo[j][e] = (_Float16)(wf - (float)hi);
          }
        }
      }
#pragma unroll
      for (int g2 = 0; g2 < 4; ++g2)
        bias4[g2] = bb[g2 * H_ + 4 * w + euu];
    }

    const bool have_h = (s > 1);
    const int  t_x    = (s <= 256) ? (s - 1) : (s - 258);
    const bool have_x = (t_x >= 0);

    f4 acc[4];
#pragma unroll
    for (int mt = 0; mt < 4; ++mt) { f4 z = {0.f, 0.f, 0.f, 0.f}; acc[mt] = z; }

    // x-GEMM first: independent of h, hides under producers' publish latency
    if (have_x) {
      for (int j = 0; j < 4; ++j) {
        if (j < nkc) {
          int kc = kbeg + j;
#pragma unroll
          for (int mt = 0; mt < 4; ++mt) {
            h8 a = *(const h8*)(xP + ((size_t)((t_x * 4 + mt) * 13 + kc) * 64 + lane) * 8);
            acc[mt] = __builtin_amdgcn_mfma_f32_16x16x32_f16(a, Ihi[j], acc[mt], 0, 0, 0);
            acc[mt] = __builtin_amdgcn_mfma_f32_16x16x32_f16(a, Ilo[j], acc[mt], 0, 0, 0);
          }
        }
      }
    }

    if (have_h) {
      // wave m consumes units [256m,256m+256) = producers 64m..64m+63:
      // each lane polls exactly one producer flag; wave reconvergence = join
      const int src = 64 * m + lane;
      const int target = s - 1;
      int it = 0;
      while (__hip_atomic_load(flags + src, __ATOMIC_RELAXED, __HIP_MEMORY_SCOPE_AGENT) < target) {
        if (++it > (1 << 20)) break;   // safety valve (diagnosable, not silent)
        __builtin_amdgcn_s_sleep(1);
      }
      asm volatile("" ::: "memory");   // no hoisting h-loads above the poll

      const _Float16* hb = ring + (size_t)((s - 1) & (RING - 1)) * (B_ * H_);
#pragma unroll
      for (int kc = 0; kc < 8; ++kc) {
#pragma unroll
        for (int mt = 0; mt < 4; ++mt) {
          h8 a = load_h16_agent(hb + (size_t)(16 * mt + ci) * H_ + m * 256 + kc * 32 + 8 * q);
          acc[mt] = __builtin_amdgcn_mfma_f32_16x16x32_f16(a, Whi[kc], acc[mt], 0, 0, 0);
          acc[mt] = __builtin_amdgcn_mfma_f32_16x16x32_f16(a, Wlo[kc], acc[mt], 0, 0, 0);
        }
      }
    }

    // split-K partials -> LDS
#pragma unroll
    for (int mt = 0; mt < 4; ++mt)
#pragma unroll
      for (int r = 0; r < 4; ++r)
        red[(m * 64 + 16 * mt + 4 * q + r) * 20 + ci] = acc[mt][r];
    __syncthreads();

    // epilogue: thread owns (b=eb_, unit uu=euu); cols 4*euu..+3 = gates i,f,g,o
    f4 sum = *(const f4*)(&red[(0 * 64 + eb_) * 20 + 4 * euu]);
#pragma unroll
    for (int mv = 1; mv < 4; ++mv)
      sum += *(const f4*)(&red[(mv * 64 + eb_) * 20 + 4 * euu]);
    float gi = sum[0] + bias4[0];
    float gf = sum[1] + bias4[1];
    float gg = sum[2] + bias4[2];
    float go = sum[3] + bias4[3];
    float cold = have_h ? c_reg : 0.f;
    float cn = sigf(gf) * cold + sigf(gi) * tanhf_(gg);
    float hn = sigf(go) * tanhf_(cn);
    c_reg = cn;
    _Float16 h16 = (_Float16)hn;
    unsigned short h16u = __builtin_bit_cast(unsigned short, h16);
    // device-coherent publish (write-through, no wbl2)
    __hip_atomic_store(
        (unsigned short*)(ring + (size_t)(s & (RING - 1)) * (B_ * H_) +
                          (size_t)eb_ * H_ + 4 * w + euu),
        h16u, __ATOMIC_RELAXED, __HIP_MEMORY_SCOPE_AGENT);
    if (s > 256)
      hs[(size_t)(s - 257) * (B_ * H_) + (size_t)eb_ * H_ + 4 * w + euu] = h16;
    if (s == 256)
      latents[(size_t)eb_ * H_ + 4 * w + euu] = hn;

    asm volatile("s_waitcnt vmcnt(0)" ::: "memory");  // sc1 acks = device-visible
    __syncthreads();
    if (tid == 0)
      __hip_atomic_store(flags + w, s, __ATOMIC_RELAXED, __HIP_MEMORY_SCOPE_AGENT);
  }
}

// ---------------- prediction head: [16384,1024] @ [1024,409] + bias ---------
__global__ __launch_bounds__(256) void pred_kernel(
    const _Float16* __restrict__ hs, const _Float16* __restrict__ PP,
    const float* __restrict__ pb, float* __restrict__ outseq)
{
  int wt = blockIdx.x * 4 + (threadIdx.x >> 6);
  int lane = threadIdx.x & 63;
  int nt = wt % 26, mt = wt / 26;
  int i = lane & 15, q = lane >> 4;
  int n = nt * 16 + i;
  float bias = (n < D_) ? pb[n] : 0.f;
  f4 acc = {bias, bias, bias, bias};
  int R = mt * 16;
#pragma unroll 4
  for (int kc = 0; kc < 32; ++kc) {
    h8 a = *(const h8*)(hs + (size_t)(R + i) * H_ + kc * 32 + 8 * q);
    h8 b = *(const h8*)(PP + ((size_t)(nt * 32 + kc) * 64 + lane) * 8);
    acc = __builtin_amdgcn_mfma_f32_16x16x32_f16(a, b, acc, 0, 0, 0);
  }
#pragma unroll
  for (int r = 0; r < 4; ++r) {
    int row = R + 4 * q + r;       // row = t*64 + b
    int t = row >> 6, bb = row & 63;
    if (n < D_) outseq[((size_t)bb * T_ + t) * D_ + n] = acc[r];
  }
}

extern "C" void kernel_launch(void* const* d_in, const int* in_sizes, int n_in,
                              void* d_out, int out_size, void* d_ws, size_t ws_size,
                              hipStream_t stream) {
  const float* inp  = (const float*)d_in[0];
  const float* eWih = (const float*)d_in[1];
  const float* eWhh = (const float*)d_in[2];
  const float* eb   = (const float*)d_in[3];
  const float* dWih = (const float*)d_in[4];
  const float* dWhh = (const float*)d_in[5];
  const float* db   = (const float*)d_in[6];
  const float* pW   = (const float*)d_in[7];
  const float* pb   = (const float*)d_in[8];
  float* out = (float*)d_out;
  float* latents = out;              // [1,64,1024]
  float* seq = out + 64 * 1024;      // [64,256,409]

  char* ws = (char*)d_ws;
  size_t off = 0;
  auto alloc = [&](size_t bytes) {
    void* p = ws + off;
    off = (off + bytes + 255) & ~(size_t)255;
    return p;
  };
  _Float16* xP  = (_Float16*)alloc((size_t)256 * 4 * 13 * 64 * 8 * 2);
  _Float16* PP  = (_Float16*)alloc((size_t)26 * 32 * 64 * 8 * 2);
  _Float16* ring= (_Float16*)alloc((size_t)RING * B_ * H_ * 2);
  _Float16* hsb = (_Float16*)alloc((size_t)256 * B_ * H_ * 2);
  int* flags    = (int*)alloc(NWG * 4);

  hipLaunchKernelGGL(prep_kernel, dim3(3536), dim3(256), 0, stream,
                     inp, pW, xP, PP, flags);
  hipLaunchKernelGGL(recur_kernel, dim3(NWG), dim3(256), 0, stream,
                     eWhh, eb, dWhh, db, eWih, dWih, xP, ring, hsb, flags, latents);
  hipLaunchKernelGGL(pred_kernel, dim3(6656), dim3(256), 0, stream,
                     hsb, PP, pb, seq);
}

// Round 4
// 5150.454 us; speedup vs baseline: 1.2750x; 1.1140x over previous
//
#include <hip/hip_runtime.h>

#define B_ 64
#define T_ 256
#define H_ 1024
#define D_ 409
#define NWG 256
#define RING 8

typedef _Float16 h8 __attribute__((ext_vector_type(8)));
typedef float f4 __attribute__((ext_vector_type(4)));
typedef unsigned u4v __attribute__((ext_vector_type(4)));

__device__ __forceinline__ float sigf(float x) {
  return 1.f / (1.f + __expf(-x));
}
__device__ __forceinline__ float tanhf_(float x) {
  return 1.f - 2.f / (1.f + __expf(2.f * x));   // saturates correctly
}

// ---------------- prep: pack x and pred_W into fp16 MFMA fragment layouts ---
// A-frag (16x16x32): lane l holds row (l&15), k = 8*(l>>4)+e
// B-frag:            lane l holds col (l&15), k = 8*(l>>4)+e
__global__ __launch_bounds__(256) void prep_kernel(
    const float* __restrict__ inp, const float* __restrict__ Pw,
    _Float16* __restrict__ xP, _Float16* __restrict__ PP)
{
  const int NX = 256 * 4 * 13 * 64;   // x frags: [t][mt][kc][lane] x 8
  const int NP = 26 * 32 * 64;        // pred frags: [nt][kc][lane] x 8
  int gid = blockIdx.x * 256 + threadIdx.x;
  if (gid < NX) {
    int lane = gid & 63; int q = gid >> 6;
    int kc = q % 13; q /= 13;
    int mt = q & 3;  int t = q >> 2;
    const float* src = inp + ((size_t)(16 * mt + (lane & 15)) * T_ + t) * D_;
    int k0 = kc * 32 + 8 * (lane >> 4);
    h8 v;
#pragma unroll
    for (int e = 0; e < 8; ++e) {
      int k = k0 + e;
      v[e] = (k < D_) ? (_Float16)src[k] : (_Float16)0.f;
    }
    *(h8*)(xP + (size_t)gid * 8) = v;
  } else if (gid < NX + NP) {
    int r = gid - NX;
    int lane = r & 63; int q = r >> 6;
    int kc = q & 31; int nt = q >> 5;
    int n = nt * 16 + (lane & 15);
    int k0 = kc * 32 + 8 * (lane >> 4);
    h8 v;
#pragma unroll
    for (int e = 0; e < 8; ++e)
      v[e] = (n < D_) ? (_Float16)Pw[(size_t)n * H_ + k0 + e] : (_Float16)0.f;
    *(h8*)(PP + (size_t)r * 8) = v;
  }
}

// 8 batched 16B loads of tagged h-words for one kc chunk (4 mt x 2 dwordx4)
#define H_ISSUE(B, A0, A1, A2, A3, BASE, FLAGS) \
  asm volatile( \
    "global_load_dwordx4 %0, %8, %12 " FLAGS "\n\t" \
    "global_load_dwordx4 %1, %8, %12 offset:16 " FLAGS "\n\t" \
    "global_load_dwordx4 %2, %9, %12 " FLAGS "\n\t" \
    "global_load_dwordx4 %3, %9, %12 offset:16 " FLAGS "\n\t" \
    "global_load_dwordx4 %4, %10, %12 " FLAGS "\n\t" \
    "global_load_dwordx4 %5, %10, %12 offset:16 " FLAGS "\n\t" \
    "global_load_dwordx4 %6, %11, %12 " FLAGS "\n\t" \
    "global_load_dwordx4 %7, %11, %12 offset:16 " FLAGS "\n\t" \
    : "=&v"(B[0]), "=&v"(B[1]), "=&v"(B[2]), "=&v"(B[3]), \
      "=&v"(B[4]), "=&v"(B[5]), "=&v"(B[6]), "=&v"(B[7]) \
    : "v"(A0), "v"(A1), "v"(A2), "v"(A3), "s"(BASE) \
    : "memory")

#define H_CHECK(BUF, MIS) do { \
  unsigned accm_ = 0u; \
  _Pragma("unroll") \
  for (int j2 = 0; j2 < 8; ++j2) { \
    u4v wv_ = BUF[j2]; \
    accm_ |= (wv_[0] ^ tw) | (wv_[1] ^ tw) | (wv_[2] ^ tw) | (wv_[3] ^ tw); \
  } \
  MIS = accm_ & 0xFFFF0000u; \
} while (0)

#define H_USE(BUF, KC) do { \
  _Pragma("unroll") \
  for (int mt_ = 0; mt_ < 4; ++mt_) { \
    u4v wa_ = BUF[2 * mt_], wb_ = BUF[2 * mt_ + 1]; \
    u4v pk_; \
    pk_[0] = __builtin_amdgcn_perm(wa_[1], wa_[0], 0x05040100u); \
    pk_[1] = __builtin_amdgcn_perm(wa_[3], wa_[2], 0x05040100u); \
    pk_[2] = __builtin_amdgcn_perm(wb_[1], wb_[0], 0x05040100u); \
    pk_[3] = __builtin_amdgcn_perm(wb_[3], wb_[2], 0x05040100u); \
    h8 av_ = __builtin_bit_cast(h8, pk_); \
    acc[mt_] = __builtin_amdgcn_mfma_f32_16x16x32_f16(av_, Whi[KC], acc[mt_], 0, 0, 0); \
    acc[mt_] = __builtin_amdgcn_mfma_f32_16x16x32_f16(av_, Wlo[KC], acc[mt_], 0, 0, 0); \
  } \
} while (0)

#define H_STEP(CUR, NXT, KC) do { \
  if ((KC) < 7) { \
    unsigned na0_ = vb0 + 128 * ((KC) + 1), na1_ = vb1 + 128 * ((KC) + 1); \
    unsigned na2_ = vb2 + 128 * ((KC) + 1), na3_ = vb3 + 128 * ((KC) + 1); \
    H_ISSUE(NXT, na0_, na1_, na2_, na3_, hb, "sc0"); \
    asm volatile("s_waitcnt vmcnt(8)" ::: "memory"); \
  } else { \
    asm volatile("s_waitcnt vmcnt(0)" ::: "memory"); \
  } \
  __builtin_amdgcn_sched_barrier(0); \
  unsigned mism_; \
  H_CHECK(CUR, mism_); \
  int guard_ = 0; \
  while (__any((int)(mism_ != 0u))) { \
    if (++guard_ > (1 << 22)) break;  /* safety valve: visible as bad absmax */ \
    unsigned ra0_ = vb0 + 128 * (KC), ra1_ = vb1 + 128 * (KC); \
    unsigned ra2_ = vb2 + 128 * (KC), ra3_ = vb3 + 128 * (KC); \
    H_ISSUE(CUR, ra0_, ra1_, ra2_, ra3_, hb, "sc0 sc1"); \
    asm volatile("s_waitcnt vmcnt(0)" ::: "memory"); \
    __builtin_amdgcn_sched_barrier(0); \
    H_CHECK(CUR, mism_); \
  } \
  H_USE(CUR, KC); \
} while (0)

// ---------------- persistent recurrent kernel: 256 WGs x 256 threads --------
// WG w owns hidden units [4w, 4w+4) -> 16 gate-cols, col c = 4*uu + g.
// Wave m = split-K slice [256m, 256m+256) of Whh (hi+lo fp16 resident VGPRs).
// h exchanged via 8-slot ring of 32-bit (tag<<16|fp16) words; no flags, no
// fences: consumers poll the tags directly with batched sc0 loads and a
// coherent (sc0 sc1) retry path. Producer stores are fire-and-forget.
__global__ __launch_bounds__(256, 1) void recur_kernel(
    const float* __restrict__ eWhh, const float* __restrict__ eb,
    const float* __restrict__ dWhh, const float* __restrict__ db,
    const float* __restrict__ eWih, const float* __restrict__ dWih,
    const _Float16* __restrict__ xP, unsigned* __restrict__ ring32,
    _Float16* __restrict__ hs, float* __restrict__ latents)
{
  __shared__ float red[4 * 64 * 20];   // [wave][row(b)][col] stride 20

  const int tid  = threadIdx.x;
  const int w    = blockIdx.x;
  const int m    = tid >> 6;
  const int lane = tid & 63;
  const int ci   = lane & 15;      // this lane's output col 0..15
  const int q    = lane >> 4;
  const int uu   = ci >> 2, g = ci & 3;
  const int nrow = g * H_ + 4 * w + uu;   // W row for this col
  const int eb_  = tid >> 2, euu = tid & 3;  // epilogue (b, unit)

  h8 Whi[8], Wlo[8], Ihi[4], Ilo[4];
  float bias4[4];
  float c_reg = 0.f;
  const int kbeg = (m == 0) ? 0 : (3 * m + 1);
  const int kend = 3 * m + 4;
  const int nkc  = kend - kbeg;

#pragma unroll 1
  for (int s = 1; s <= 512; ++s) {
    if (s == 1 || s == 257) {
      const float* Whh = (s == 1) ? eWhh : dWhh;
      const float* Wih = (s == 1) ? eWih : dWih;
      const float* bb  = (s == 1) ? eb : db;
#pragma unroll
      for (int kc = 0; kc < 8; ++kc) {
        const float* p = Whh + (size_t)nrow * H_ + m * 256 + kc * 32 + 8 * q;
#pragma unroll
        for (int e = 0; e < 8; ++e) {
          float wf = p[e];
          _Float16 hi = (_Float16)wf;
          Whi[kc][e] = hi;
          Wlo[kc][e] = (_Float16)(wf - (float)hi);
        }
      }
      for (int j = 0; j < 4; ++j) {
        if (j < nkc) {
          int kc = kbeg + j;
          int k0 = kc * 32 + 8 * q;
#pragma unroll
          for (int e = 0; e < 8; ++e) {
            int k = k0 + e;
            float wf = (k < D_) ? Wih[(size_t)nrow * D_ + k] : 0.f;
            _Float16 hi = (_Float16)wf;
            Ihi[j][e] = hi;
            Ilo[j][e] = (_Float16)(wf - (float)hi);
          }
        }
      }
#pragma unroll
      for (int g2 = 0; g2 < 4; ++g2)
        bias4[g2] = bb[g2 * H_ + 4 * w + euu];
    }

    const bool have_h = (s > 1);
    const int  t_x    = (s <= 256) ? (s - 1) : (s - 258);
    const bool have_x = (t_x >= 0);

    f4 acc[4];
#pragma unroll
    for (int mt = 0; mt < 4; ++mt) { f4 z = {0.f, 0.f, 0.f, 0.f}; acc[mt] = z; }

    // x-GEMM first: independent of h, overlaps other WGs' h publication
    if (have_x) {
      for (int j = 0; j < 4; ++j) {
        if (j < nkc) {
          int kc = kbeg + j;
#pragma unroll
          for (int mt = 0; mt < 4; ++mt) {
            h8 a = *(const h8*)(xP + ((size_t)((t_x * 4 + mt) * 13 + kc) * 64 + lane) * 8);
            acc[mt] = __builtin_amdgcn_mfma_f32_16x16x32_f16(a, Ihi[j], acc[mt], 0, 0, 0);
            acc[mt] = __builtin_amdgcn_mfma_f32_16x16x32_f16(a, Ilo[j], acc[mt], 0, 0, 0);
          }
        }
      }
    }

    if (have_h) {
      const unsigned* hb = ring32 + (size_t)((s - 1) & (RING - 1)) * (B_ * H_);
      const unsigned tw = (unsigned)(s - 1) << 16;
      // per-mt byte offsets of this lane's 8 words (row 16mt+ci, k = 8q..)
      unsigned vb0 = (unsigned)(((0 * 16 + ci) * H_ + m * 256 + 8 * q) * 4);
      unsigned vb1 = vb0 + 16 * H_ * 4;
      unsigned vb2 = vb1 + 16 * H_ * 4;
      unsigned vb3 = vb2 + 16 * H_ * 4;
      u4v BA[8], BB[8];
      asm volatile("s_waitcnt vmcnt(0)" ::: "memory");  // drain prior-step stores
      H_ISSUE(BA, vb0, vb1, vb2, vb3, hb, "sc0");
#pragma unroll
      for (int kc = 0; kc < 8; ++kc) {
        if ((kc & 1) == 0) H_STEP(BA, BB, kc); else H_STEP(BB, BA, kc);
      }
    }

    // split-K partials -> LDS
#pragma unroll
    for (int mt = 0; mt < 4; ++mt)
#pragma unroll
      for (int r = 0; r < 4; ++r)
        red[(m * 64 + 16 * mt + 4 * q + r) * 20 + ci] = acc[mt][r];
    __syncthreads();

    // epilogue: thread owns (b=eb_, unit uu=euu); cols 4*euu..+3 = gates i,f,g,o
    f4 sum = *(const f4*)(&red[(0 * 64 + eb_) * 20 + 4 * euu]);
#pragma unroll
    for (int mv = 1; mv < 4; ++mv)
      sum += *(const f4*)(&red[(mv * 64 + eb_) * 20 + 4 * euu]);
    float gi = sum[0] + bias4[0];
    float gf = sum[1] + bias4[1];
    float gg = sum[2] + bias4[2];
    float go = sum[3] + bias4[3];
    float cold = have_h ? c_reg : 0.f;
    float cn = sigf(gf) * cold + sigf(gi) * tanhf_(gg);
    float hn = sigf(go) * tanhf_(cn);
    c_reg = cn;
    _Float16 h16 = (_Float16)hn;
    unsigned short h16u = __builtin_bit_cast(unsigned short, h16);
    unsigned word = ((unsigned)s << 16) | (unsigned)h16u;
    // fire-and-forget device-visible publish; tag IS the flag
    __hip_atomic_store(
        ring32 + (size_t)(s & (RING - 1)) * (B_ * H_) + (size_t)eb_ * H_ + 4 * w + euu,
        word, __ATOMIC_RELAXED, __HIP_MEMORY_SCOPE_AGENT);
    if (s > 256)
      hs[(size_t)(s - 257) * (B_ * H_) + (size_t)eb_ * H_ + 4 * w + euu] = h16;
    if (s == 256)
      latents[(size_t)eb_ * H_ + 4 * w + euu] = hn;

    __syncthreads();   // red reuse fence (no publish protocol anymore)
  }
}

// ---------------- prediction head: [16384,1024] @ [1024,409] + bias ---------
__global__ __launch_bounds__(256) void pred_kernel(
    const _Float16* __restrict__ hs, const _Float16* __restrict__ PP,
    const float* __restrict__ pb, float* __restrict__ outseq)
{
  int wt = blockIdx.x * 4 + (threadIdx.x >> 6);
  int lane = threadIdx.x & 63;
  int nt = wt % 26, mt = wt / 26;
  int i = lane & 15, q = lane >> 4;
  int n = nt * 16 + i;
  float bias = (n < D_) ? pb[n] : 0.f;
  f4 acc = {bias, bias, bias, bias};
  int R = mt * 16;
#pragma unroll 4
  for (int kc = 0; kc < 32; ++kc) {
    h8 a = *(const h8*)(hs + (size_t)(R + i) * H_ + kc * 32 + 8 * q);
    h8 b = *(const h8*)(PP + ((size_t)(nt * 32 + kc) * 64 + lane) * 8);
    acc = __builtin_amdgcn_mfma_f32_16x16x32_f16(a, b, acc, 0, 0, 0);
  }
#pragma unroll
  for (int r = 0; r < 4; ++r) {
    int row = R + 4 * q + r;       // row = t*64 + b
    int t = row >> 6, bb = row & 63;
    if (n < D_) outseq[((size_t)bb * T_ + t) * D_ + n] = acc[r];
  }
}

extern "C" void kernel_launch(void* const* d_in, const int* in_sizes, int n_in,
                              void* d_out, int out_size, void* d_ws, size_t ws_size,
                              hipStream_t stream) {
  const float* inp  = (const float*)d_in[0];
  const float* eWih = (const float*)d_in[1];
  const float* eWhh = (const float*)d_in[2];
  const float* eb   = (const float*)d_in[3];
  const float* dWih = (const float*)d_in[4];
  const float* dWhh = (const float*)d_in[5];
  const float* db   = (const float*)d_in[6];
  const float* pW   = (const float*)d_in[7];
  const float* pb   = (const float*)d_in[8];
  float* out = (float*)d_out;
  float* latents = out;              // [1,64,1024]
  float* seq = out + 64 * 1024;      // [64,256,409]

  char* ws = (char*)d_ws;
  size_t off = 0;
  auto alloc = [&](size_t bytes) {
    void* p = ws + off;
    off = (off + bytes + 255) & ~(size_t)255;
    return p;
  };
  _Float16* xP   = (_Float16*)alloc((size_t)256 * 4 * 13 * 64 * 8 * 2);
  _Float16* PP   = (_Float16*)alloc((size_t)26 * 32 * 64 * 8 * 2);
  unsigned* ring32 = (unsigned*)alloc((size_t)RING * B_ * H_ * 4);
  _Float16* hsb  = (_Float16*)alloc((size_t)256 * B_ * H_ * 2);

  hipLaunchKernelGGL(prep_kernel, dim3(3536), dim3(256), 0, stream,
                     inp, pW, xP, PP);
  hipLaunchKernelGGL(recur_kernel, dim3(NWG), dim3(256), 0, stream,
                     eWhh, eb, dWhh, db, eWih, dWih, xP, ring32, hsb, latents);
  hipLaunchKernelGGL(pred_kernel, dim3(6656), dim3(256), 0, stream,
                     hsb, PP, pb, seq);
}

// Round 5
// 3671.150 us; speedup vs baseline: 1.7887x; 1.4030x over previous
//
#include <hip/hip_runtime.h>

#define B_ 64
#define T_ 256
#define H_ 1024
#define D_ 409
#define NWG 256
#define NSLOT 513   // slot s holds h after step s (s=1..512); slot 0 unused

typedef _Float16 h8 __attribute__((ext_vector_type(8)));
typedef float f4 __attribute__((ext_vector_type(4)));
typedef unsigned u4v __attribute__((ext_vector_type(4)));

__device__ __forceinline__ float sigf(float x) {
  return 1.f / (1.f + __expf(-x));
}
__device__ __forceinline__ float tanhf_(float x) {
  return 1.f - 2.f / (1.f + __expf(2.f * x));   // saturates correctly
}

// ---------------- prep: pack x and pred_W into fp16 MFMA fragment layouts ---
// A-frag (16x16x32): lane l holds row (l&15), k = 8*(l>>4)+e
// B-frag:            lane l holds col (l&15), k = 8*(l>>4)+e
__global__ __launch_bounds__(256) void prep_kernel(
    const float* __restrict__ inp, const float* __restrict__ Pw,
    _Float16* __restrict__ xP, _Float16* __restrict__ PP,
    int* __restrict__ flags)
{
  const int NX = 256 * 4 * 13 * 64;   // x frags: [t][mt][kc][lane] x 8
  const int NP = 26 * 32 * 64;        // pred frags: [nt][kc][lane] x 8
  int gid = blockIdx.x * 256 + threadIdx.x;
  if (gid < NWG) flags[gid] = 0;      // stream-ordered before recur launch
  if (gid < NX) {
    int lane = gid & 63; int q = gid >> 6;
    int kc = q % 13; q /= 13;
    int mt = q & 3;  int t = q >> 2;
    const float* src = inp + ((size_t)(16 * mt + (lane & 15)) * T_ + t) * D_;
    int k0 = kc * 32 + 8 * (lane >> 4);
    h8 v;
#pragma unroll
    for (int e = 0; e < 8; ++e) {
      int k = k0 + e;
      v[e] = (k < D_) ? (_Float16)src[k] : (_Float16)0.f;
    }
    *(h8*)(xP + (size_t)gid * 8) = v;
  } else if (gid < NX + NP) {
    int r = gid - NX;
    int lane = r & 63; int q = r >> 6;
    int kc = q & 31; int nt = q >> 5;
    int n = nt * 16 + (lane & 15);
    int k0 = kc * 32 + 8 * (lane >> 4);
    h8 v;
#pragma unroll
    for (int e = 0; e < 8; ++e)
      v[e] = (n < D_) ? (_Float16)Pw[(size_t)n * H_ + k0 + e] : (_Float16)0.f;
    *(h8*)(PP + (size_t)r * 8) = v;
  }
}

// issue 4 cached dwordx4 h-loads (one kc chunk: rows 16mt+ci, 16B each)
#define H_ISS(KC, OFFB) \
  asm volatile( \
    "global_load_dwordx4 %0, %4, %8 offset:" #OFFB "\n\t" \
    "global_load_dwordx4 %1, %5, %8 offset:" #OFFB "\n\t" \
    "global_load_dwordx4 %2, %6, %8 offset:" #OFFB "\n\t" \
    "global_load_dwordx4 %3, %7, %8 offset:" #OFFB "\n\t" \
    : "=&v"(BH[KC][0]), "=&v"(BH[KC][1]), "=&v"(BH[KC][2]), "=&v"(BH[KC][3]) \
    : "v"(va0), "v"(va1), "v"(va2), "v"(va3), "s"(hb) \
    : "memory")

// counted wait: chunk KC complete when vmcnt <= 28-4*KC (kc-major issue order)
#define HWAIT(N) do { \
  asm volatile("s_waitcnt vmcnt(" #N ")" ::: "memory"); \
  __builtin_amdgcn_sched_barrier(0); \
} while (0)

#define HCONS(KC) do { \
  _Pragma("unroll") \
  for (int mt_ = 0; mt_ < 4; ++mt_) { \
    h8 av_ = __builtin_bit_cast(h8, BH[KC][mt_]); \
    acc[mt_] = __builtin_amdgcn_mfma_f32_16x16x32_f16(av_, Whi[KC], acc[mt_], 0, 0, 0); \
    acc[mt_] = __builtin_amdgcn_mfma_f32_16x16x32_f16(av_, Wlo[KC], acc[mt_], 0, 0, 0); \
  } \
} while (0)

// ---------------- persistent recurrent kernel: 256 WGs x 256 threads --------
// WG w owns hidden units [4w,4w+4) -> 16 gate-cols (col = 4*uu + gate).
// Wave m = split-K slice [256m,256m+256) of Whh (hi+lo fp16 resident VGPRs).
// h exchanged via NON-REUSED ring (slot per step, plain fp16): an address is
// read only after its producer's flag (stored after vmcnt(0)-drained sc1
// stores) -> no stale line can ever enter L1/L2 -> plain cached loads, fully
// pipelined with counted vmcnt, 32x L2 reuse per XCD. No tags, no retries.
__global__ __launch_bounds__(256, 1) void recur_kernel(
    const float* __restrict__ eWhh, const float* __restrict__ eb,
    const float* __restrict__ dWhh, const float* __restrict__ db,
    const float* __restrict__ eWih, const float* __restrict__ dWih,
    const _Float16* __restrict__ xP, _Float16* __restrict__ ring,
    int* __restrict__ flags, float* __restrict__ latents)
{
  __shared__ float red[4 * 64 * 20];   // [wave][row(b)][col] stride 20

  const int tid  = threadIdx.x;
  const int w    = blockIdx.x;
  const int m    = tid >> 6;
  const int lane = tid & 63;
  const int ci   = lane & 15;      // this lane's output col 0..15
  const int q    = lane >> 4;
  const int uu   = ci >> 2, g = ci & 3;
  const int nrow = g * H_ + 4 * w + uu;   // W row for this col
  const int eb_  = tid >> 2, euu = tid & 3;  // epilogue (b, unit)

  h8 Whi[8], Wlo[8], Ihi[4], Ilo[4];
  float bias4[4];
  float c_reg = 0.f;
  const int kbeg = (m == 0) ? 0 : (3 * m + 1);
  const int kend = 3 * m + 4;
  const int nkc  = kend - kbeg;

  // per-lane byte offsets of the 4 mt-rows within a ring slot
  const unsigned colb = (unsigned)((m * 256 + 8 * q) * 2);
  const unsigned va0 = (unsigned)(ci * H_ * 2) + colb;
  const unsigned va1 = va0 + 16 * H_ * 2;
  const unsigned va2 = va1 + 16 * H_ * 2;
  const unsigned va3 = va2 + 16 * H_ * 2;

#pragma unroll 1
  for (int s = 1; s <= 512; ++s) {
    if (s == 1 || s == 257) {
      const float* Whh = (s == 1) ? eWhh : dWhh;
      const float* Wih = (s == 1) ? eWih : dWih;
      const float* bb  = (s == 1) ? eb : db;
#pragma unroll
      for (int kc = 0; kc < 8; ++kc) {
        const float* p = Whh + (size_t)nrow * H_ + m * 256 + kc * 32 + 8 * q;
#pragma unroll
        for (int e = 0; e < 8; ++e) {
          float wf = p[e];
          _Float16 hi = (_Float16)wf;
          Whi[kc][e] = hi;
          Wlo[kc][e] = (_Float16)(wf - (float)hi);
        }
      }
      for (int j = 0; j < 4; ++j) {
        if (j < nkc) {
          int kc = kbeg + j;
          int k0 = kc * 32 + 8 * q;
#pragma unroll
          for (int e = 0; e < 8; ++e) {
            int k = k0 + e;
            float wf = (k < D_) ? Wih[(size_t)nrow * D_ + k] : 0.f;
            _Float16 hi = (_Float16)wf;
            Ihi[j][e] = hi;
            Ilo[j][e] = (_Float16)(wf - (float)hi);
          }
        }
      }
#pragma unroll
      for (int g2 = 0; g2 < 4; ++g2)
        bias4[g2] = bb[g2 * H_ + 4 * w + euu];
    }

    const bool have_h = (s > 1);
    const int  t_x    = (s <= 256) ? (s - 1) : (s - 258);
    const bool have_x = (t_x >= 0);

    f4 acc[4];
#pragma unroll
    for (int mt = 0; mt < 4; ++mt) { f4 z = {0.f, 0.f, 0.f, 0.f}; acc[mt] = z; }

    // x-GEMM first: independent of h, overlaps producers' publish window
    if (have_x) {
      for (int j = 0; j < 4; ++j) {
        if (j < nkc) {
          int kc = kbeg + j;
#pragma unroll
          for (int mt = 0; mt < 4; ++mt) {
            h8 a = *(const h8*)(xP + ((size_t)((t_x * 4 + mt) * 13 + kc) * 64 + lane) * 8);
            acc[mt] = __builtin_amdgcn_mfma_f32_16x16x32_f16(a, Ihi[j], acc[mt], 0, 0, 0);
            acc[mt] = __builtin_amdgcn_mfma_f32_16x16x32_f16(a, Ilo[j], acc[mt], 0, 0, 0);
          }
        }
      }
    }

    if (have_h) {
      // clean vmcnt slate (drains prior-step stores + x loads)
      asm volatile("s_waitcnt vmcnt(0)" ::: "memory");
      // wave m's K-slice is produced by WGs [64m, 64m+64): one flag per lane
      {
        int* fp = flags + 64 * m + lane;
        const int target = s - 1;
        int it = 0;
        while (__hip_atomic_load(fp, __ATOMIC_RELAXED, __HIP_MEMORY_SCOPE_AGENT) < target) {
          if (++it > (1 << 20)) break;   // safety valve (shows as bad absmax)
        }
      }
      asm volatile("" ::: "memory");     // no hoisting loads above the poll

      const _Float16* hb = ring + (size_t)(s - 1) * (B_ * H_);
      u4v BH[8][4];
      H_ISS(0, 0);   H_ISS(1, 64);  H_ISS(2, 128); H_ISS(3, 192);
      H_ISS(4, 256); H_ISS(5, 320); H_ISS(6, 384); H_ISS(7, 448);
      HWAIT(28); HCONS(0);
      HWAIT(24); HCONS(1);
      HWAIT(20); HCONS(2);
      HWAIT(16); HCONS(3);
      HWAIT(12); HCONS(4);
      HWAIT(8);  HCONS(5);
      HWAIT(4);  HCONS(6);
      HWAIT(0);  HCONS(7);
    }

    // split-K partials -> LDS
#pragma unroll
    for (int mt = 0; mt < 4; ++mt)
#pragma unroll
      for (int r = 0; r < 4; ++r)
        red[(m * 64 + 16 * mt + 4 * q + r) * 20 + ci] = acc[mt][r];
    __syncthreads();

    // epilogue: thread owns (b=eb_, unit uu=euu); cols 4*euu..+3 = gates i,f,g,o
    f4 sum = *(const f4*)(&red[(0 * 64 + eb_) * 20 + 4 * euu]);
#pragma unroll
    for (int mv = 1; mv < 4; ++mv)
      sum += *(const f4*)(&red[(mv * 64 + eb_) * 20 + 4 * euu]);
    float gi = sum[0] + bias4[0];
    float gf = sum[1] + bias4[1];
    float gg = sum[2] + bias4[2];
    float go = sum[3] + bias4[3];
    float cold = have_h ? c_reg : 0.f;
    float cn = sigf(gf) * cold + sigf(gi) * tanhf_(gg);
    float hn = sigf(go) * tanhf_(cn);
    c_reg = cn;
    _Float16 h16 = (_Float16)hn;
    unsigned short h16u = __builtin_bit_cast(unsigned short, h16);
    // device-visible publish into this step's fresh slot (write-through sc1)
    __hip_atomic_store(
        (unsigned short*)(ring + (size_t)s * (B_ * H_) + (size_t)eb_ * H_ + 4 * w + euu),
        h16u, __ATOMIC_RELAXED, __HIP_MEMORY_SCOPE_AGENT);
    if (s == 256)
      latents[(size_t)eb_ * H_ + 4 * w + euu] = hn;

    asm volatile("s_waitcnt vmcnt(0)" ::: "memory");  // store acks = MALL-visible
    __syncthreads();                                  // all waves drained
    if (tid == 0)
      __hip_atomic_store(flags + w, s, __ATOMIC_RELAXED, __HIP_MEMORY_SCOPE_AGENT);
  }
}

// ---------------- prediction head: [16384,1024] @ [1024,409] + bias ---------
// hs = ring slots 257..512 (decoder outputs), layout [t][b][H] fp16
__global__ __launch_bounds__(256) void pred_kernel(
    const _Float16* __restrict__ hs, const _Float16* __restrict__ PP,
    const float* __restrict__ pb, float* __restrict__ outseq)
{
  int wt = blockIdx.x * 4 + (threadIdx.x >> 6);
  int lane = threadIdx.x & 63;
  int nt = wt % 26, mt = wt / 26;
  int i = lane & 15, q = lane >> 4;
  int n = nt * 16 + i;
  float bias = (n < D_) ? pb[n] : 0.f;
  f4 acc = {bias, bias, bias, bias};
  int R = mt * 16;
#pragma unroll 4
  for (int kc = 0; kc < 32; ++kc) {
    h8 a = *(const h8*)(hs + (size_t)(R + i) * H_ + kc * 32 + 8 * q);
    h8 b = *(const h8*)(PP + ((size_t)(nt * 32 + kc) * 64 + lane) * 8);
    acc = __builtin_amdgcn_mfma_f32_16x16x32_f16(a, b, acc, 0, 0, 0);
  }
#pragma unroll
  for (int r = 0; r < 4; ++r) {
    int row = R + 4 * q + r;       // row = t*64 + b
    int t = row >> 6, bb = row & 63;
    if (n < D_) outseq[((size_t)bb * T_ + t) * D_ + n] = acc[r];
  }
}

extern "C" void kernel_launch(void* const* d_in, const int* in_sizes, int n_in,
                              void* d_out, int out_size, void* d_ws, size_t ws_size,
                              hipStream_t stream) {
  const float* inp  = (const float*)d_in[0];
  const float* eWih = (const float*)d_in[1];
  const float* eWhh = (const float*)d_in[2];
  const float* eb   = (const float*)d_in[3];
  const float* dWih = (const float*)d_in[4];
  const float* dWhh = (const float*)d_in[5];
  const float* db   = (const float*)d_in[6];
  const float* pW   = (const float*)d_in[7];
  const float* pb   = (const float*)d_in[8];
  float* out = (float*)d_out;
  float* latents = out;              // [1,64,1024]
  float* seq = out + 64 * 1024;      // [64,256,409]

  char* ws = (char*)d_ws;
  size_t off = 0;
  auto alloc = [&](size_t bytes) {
    void* p = ws + off;
    off = (off + bytes + 255) & ~(size_t)255;
    return p;
  };
  _Float16* xP   = (_Float16*)alloc((size_t)256 * 4 * 13 * 64 * 8 * 2);
  _Float16* PP   = (_Float16*)alloc((size_t)26 * 32 * 64 * 8 * 2);
  _Float16* ring = (_Float16*)alloc((size_t)NSLOT * B_ * H_ * 2);
  int* flags     = (int*)alloc(NWG * 4);

  hipLaunchKernelGGL(prep_kernel, dim3(3536), dim3(256), 0, stream,
                     inp, pW, xP, PP, flags);
  hipLaunchKernelGGL(recur_kernel, dim3(NWG), dim3(256), 0, stream,
                     eWhh, eb, dWhh, db, eWih, dWih, xP, ring, flags, latents);
  hipLaunchKernelGGL(pred_kernel, dim3(6656), dim3(256), 0, stream,
                     ring + (size_t)257 * B_ * H_, PP, pb, seq);
}